// Round 1
// baseline (4596.146 us; speedup 1.0000x reference)
//
#include <hip/hip_runtime.h>

// RGCN 2-layer encoder, fp32.
// out[i] = sum_r (1/|N_r(i)|) sum_{j in N_r(i)} x[j]@W_r  +  x[i]@W_root + b
// Strategy:
//   - One fused GEMM per layer computing root projection (-> accumulator, +bias)
//     and all R relation projections (-> Hrel[R][N][HD]).
//   - Edge histogram (atomic int) -> norm table 1/max(cnt,1), computed once,
//     reused by both layers (same edges).
//   - Scatter: thread per (edge, 4-feature chunk): float4 gather from Hrel
//     (L3-resident), 4 scalar fp32 atomics into [N,HD] accumulator.
//   - ReLU between layers.

#define RNUM 4
constexpr int IN_DIM  = 1024;
constexpr int HID     = 128;
constexpr int OUT_DIM = 32;

// ---------------- counting ----------------
__global__ void count_edges(const int* __restrict__ dstv,
                            const int* __restrict__ etv,
                            int E, int* __restrict__ counts) {
    int i = blockIdx.x * blockDim.x + threadIdx.x;
    if (i < E) atomicAdd(&counts[dstv[i] * RNUM + etv[i]], 1);
}

__global__ void make_norm(const int* __restrict__ counts, int n,
                          float* __restrict__ norm) {
    int i = blockIdx.x * blockDim.x + threadIdx.x;
    if (i < n) norm[i] = 1.0f / fmaxf((float)counts[i], 1.0f);
}

// ---------------- fused GEMM ----------------
// A[M,K] x {Broot[K,HD] | Wrel[R,K,HD]} -> Cacc[M,HD] (+bias) and Crel[R,M,HD]
// Column index j in [0, (R+1)*HD): j<HD -> root, else relation (j-HD)/HD.
// BN <= HD and HD % BN == 0 so a column block never straddles matrices.
template<int BM, int BN, int BK, int TM, int TN, int HD>
__global__ __launch_bounds__(256)
void gemm_fused(const float* __restrict__ A,
                const float* __restrict__ Broot,
                const float* __restrict__ Wrel,
                const float* __restrict__ bias,
                float* __restrict__ Cacc,
                float* __restrict__ Crel,
                int M, int K)
{
    constexpr int TX = BN / TN;   // threads along N
    constexpr int TY = BM / TM;   // threads along M
    static_assert(TX * TY == 256, "block must be 256 threads");

    const int tid  = threadIdx.x;
    const int tx   = tid % TX;
    const int ty   = tid / TX;
    const int j0   = blockIdx.x * BN;
    const int row0 = blockIdx.y * BM;

    const bool isRoot = (j0 < HD);
    int r = 0, c0 = j0;
    const float* Bptr;
    if (isRoot) {
        Bptr = Broot + c0;
    } else {
        r  = (j0 - HD) / HD;
        c0 = (j0 - HD) % HD;
        Bptr = Wrel + (size_t)r * K * HD + c0;
    }

    __shared__ float As[BK][BM + 1];  // +1 pad: conflict-free transposed stores
    __shared__ float Bs[BK][BN];      // unpadded: aligned float4, 2-way max (free)

    float acc[TM][TN] = {};

    for (int k0 = 0; k0 < K; k0 += BK) {
        // ---- load A tile (BM x BK), transpose into As[k][row]
        {
            constexpr int KQ = BK / 4;          // float4s per A row
            int rowi = tid / KQ;
            int kq   = tid % KQ;                // BM*KQ == 256 for BM=64,BK=16
            float4 av = make_float4(0.f, 0.f, 0.f, 0.f);
            int grow = row0 + rowi;
            if (grow < M)
                av = *reinterpret_cast<const float4*>(&A[(size_t)grow * K + k0 + kq * 4]);
            As[kq * 4 + 0][rowi] = av.x;
            As[kq * 4 + 1][rowi] = av.y;
            As[kq * 4 + 2][rowi] = av.z;
            As[kq * 4 + 3][rowi] = av.w;
        }
        // ---- load B tile (BK x BN)
        {
            constexpr int BF4 = BN / 4;
            constexpr int TOT = BK * BF4;
            if (TOT >= 256 || tid < TOT) {
                int k  = tid / BF4;
                int jq = tid % BF4;
                float4 bv = *reinterpret_cast<const float4*>(
                    &Bptr[(size_t)(k0 + k) * HD + jq * 4]);
                *reinterpret_cast<float4*>(&Bs[k][jq * 4]) = bv;
            }
        }
        __syncthreads();

        #pragma unroll
        for (int k = 0; k < BK; ++k) {
            float aF[TM], bF[TN];
            #pragma unroll
            for (int m = 0; m < TM; ++m) aF[m] = As[k][ty * TM + m];
            #pragma unroll
            for (int n = 0; n < TN; ++n) bF[n] = Bs[k][tx * TN + n];
            #pragma unroll
            for (int m = 0; m < TM; ++m)
                #pragma unroll
                for (int n = 0; n < TN; ++n)
                    acc[m][n] += aF[m] * bF[n];
        }
        __syncthreads();
    }

    // ---- store (vectorized)
    #pragma unroll
    for (int m = 0; m < TM; ++m) {
        int grow = row0 + ty * TM + m;
        if (grow >= M) continue;
        float tmp[TN];
        #pragma unroll
        for (int n = 0; n < TN; ++n)
            tmp[n] = acc[m][n] + (isRoot ? bias[c0 + tx * TN + n] : 0.f);
        float* dstp = isRoot
            ? &Cacc[(size_t)grow * HD + c0 + tx * TN]
            : &Crel[((size_t)r * M + grow) * HD + c0 + tx * TN];
        if constexpr (TN == 4) {
            *reinterpret_cast<float4*>(dstp) =
                make_float4(tmp[0], tmp[1], tmp[2], tmp[3]);
        } else if constexpr (TN == 2) {
            *reinterpret_cast<float2*>(dstp) = make_float2(tmp[0], tmp[1]);
        } else {
            #pragma unroll
            for (int n = 0; n < TN; ++n) dstp[n] = tmp[n];
        }
    }
}

// ---------------- scatter (gather + normalized atomic accumulate) ----------------
template<int HD>
__global__ void scatter_mean(const float* __restrict__ Hrel,   // [R,N,HD]
                             const int* __restrict__ srcv,
                             const int* __restrict__ dstv,
                             const int* __restrict__ etv,
                             const float* __restrict__ norm,   // [N*R]
                             float* __restrict__ outp,         // [N,HD]
                             int E, int N)
{
    constexpr int TPE = HD / 4;   // threads per edge (4 feats each)
    int i = blockIdx.x * blockDim.x + threadIdx.x;
    int total = E * TPE;
    if (i >= total) return;
    int e = i / TPE;
    int f = (i % TPE) * 4;
    int s = srcv[e];
    int d = dstv[e];
    int t = etv[e];
    float nrm = norm[d * RNUM + t];
    float4 v = *reinterpret_cast<const float4*>(
        &Hrel[((size_t)t * N + s) * HD + f]);
    float* o = &outp[(size_t)d * HD + f];
    atomicAdd(o + 0, v.x * nrm);
    atomicAdd(o + 1, v.y * nrm);
    atomicAdd(o + 2, v.z * nrm);
    atomicAdd(o + 3, v.w * nrm);
}

__global__ void relu_k(float* __restrict__ p, int n) {
    int i = blockIdx.x * blockDim.x + threadIdx.x;
    if (i < n) p[i] = fmaxf(p[i], 0.f);
}

// ---------------- launch ----------------
extern "C" void kernel_launch(void* const* d_in, const int* in_sizes, int n_in,
                              void* d_out, int out_size, void* d_ws, size_t ws_size,
                              hipStream_t stream)
{
    const float* x     = (const float*)d_in[0];
    const int*   ei    = (const int*)d_in[1];
    const int*   et    = (const int*)d_in[2];
    const float* W1    = (const float*)d_in[3];
    const float* root1 = (const float*)d_in[4];
    const float* b1    = (const float*)d_in[5];
    const float* W2    = (const float*)d_in[6];
    const float* root2 = (const float*)d_in[7];
    const float* b2    = (const float*)d_in[8];
    float* out = (float*)d_out;

    const int N = in_sizes[0] / IN_DIM;   // 50000
    const int E = in_sizes[1] / 2;        // 1,600,000
    const int* srcv = ei;
    const int* dstv = ei + E;

    // workspace layout (floats): H1[R*N*HID] | hacc[N*HID] | H2[R*N*OUT] | counts | norm
    float* H1   = (float*)d_ws;
    float* hacc = H1 + (size_t)RNUM * N * HID;
    float* H2   = hacc + (size_t)N * HID;
    int*   counts = (int*)(H2 + (size_t)RNUM * N * OUT_DIM);
    float* norm   = (float*)(counts + (size_t)N * RNUM);

    // --- edge histogram + norm table (shared by both layers)
    hipMemsetAsync(counts, 0, (size_t)N * RNUM * sizeof(int), stream);
    count_edges<<<(E + 255) / 256, 256, 0, stream>>>(dstv, et, E, counts);
    make_norm<<<(N * RNUM + 255) / 256, 256, 0, stream>>>(counts, N * RNUM, norm);

    // --- layer 1: projections (root -> hacc with bias, relations -> H1)
    dim3 g1((RNUM + 1) * HID / 64, (N + 63) / 64);
    gemm_fused<64, 64, 16, 4, 4, HID>
        <<<g1, 256, 0, stream>>>(x, root1, W1, b1, hacc, H1, N, IN_DIM);

    int s1total = E * (HID / 4);
    scatter_mean<HID><<<(s1total + 255) / 256, 256, 0, stream>>>(
        H1, srcv, dstv, et, norm, hacc, E, N);

    relu_k<<<(N * HID + 255) / 256, 256, 0, stream>>>(hacc, N * HID);

    // --- layer 2: projections (root -> out with bias, relations -> H2)
    dim3 g2((RNUM + 1) * OUT_DIM / 32, (N + 63) / 64);
    gemm_fused<64, 32, 16, 4, 2, OUT_DIM>
        <<<g2, 256, 0, stream>>>(hacc, root2, W2, b2, out, H2, N, HID);

    int s2total = E * (OUT_DIM / 4);
    scatter_mean<OUT_DIM><<<(s2total + 255) / 256, 256, 0, stream>>>(
        H2, srcv, dstv, et, norm, out, E, N);
}

// Round 2
// 1629.056 us; speedup vs baseline: 2.8214x; 2.8214x over previous
//
#include <hip/hip_runtime.h>

// RGCN 2-layer encoder, fp32.
// out[i] = sum_r (1/|N_r(i)|) sum_{j in N_r(i)} x[j]@W_r  +  x[i]@W_root + b
//
// R1 change: replace per-edge atomic scatter (was 2.68ms, atomic-bound,
// VALUBusy 1.6%) with device-built CSR (counting sort by seg=dst*R+rel)
// + owner-computes segmented reduction (zero fp32 atomics).

#define RNUM 4
constexpr int IN_DIM  = 1024;
constexpr int HID     = 128;
constexpr int OUT_DIM = 32;

// ---------------- histogram ----------------
__global__ void count_edges(const int* __restrict__ dstv,
                            const int* __restrict__ etv,
                            int E, int* __restrict__ counts) {
    int i = blockIdx.x * blockDim.x + threadIdx.x;
    if (i < E) atomicAdd(&counts[dstv[i] * RNUM + etv[i]], 1);
}

// ---------------- exclusive scan over NR=200k (3 kernels) ----------------
// chunk = 1024 elems per 256-thread block
__global__ void scan_reduce(const int* __restrict__ counts, int n,
                            int* __restrict__ bsum) {
    __shared__ int sdata[256];
    int t = threadIdx.x;
    int base = blockIdx.x * 1024;
    int sum = 0;
    #pragma unroll
    for (int k = 0; k < 4; ++k) {
        int i = base + t * 4 + k;
        if (i < n) sum += counts[i];
    }
    sdata[t] = sum; __syncthreads();
    for (int off = 128; off > 0; off >>= 1) {
        if (t < off) sdata[t] += sdata[t + off];
        __syncthreads();
    }
    if (t == 0) bsum[blockIdx.x] = sdata[0];
}

__global__ void scan_bsum(int* __restrict__ bsum, int nb) {
    if (threadIdx.x == 0 && blockIdx.x == 0) {
        int acc = 0;
        for (int i = 0; i < nb; ++i) { int v = bsum[i]; bsum[i] = acc; acc += v; }
    }
}

__global__ void scan_apply(const int* __restrict__ counts,
                           const int* __restrict__ bsum_excl,
                           int n, int E, int* __restrict__ rowptr) {
    __shared__ int sdata[256];
    int t = threadIdx.x;
    int base = blockIdx.x * 1024;
    int idx = base + t * 4;
    int v[4]; int sum = 0;
    #pragma unroll
    for (int k = 0; k < 4; ++k) {
        int i = idx + k;
        v[k] = (i < n) ? counts[i] : 0;
        sum += v[k];
    }
    sdata[t] = sum; __syncthreads();
    // Hillis-Steele inclusive scan over 256 thread-sums
    for (int off = 1; off < 256; off <<= 1) {
        int x = (t >= off) ? sdata[t - off] : 0;
        __syncthreads();
        sdata[t] += x;
        __syncthreads();
    }
    int run = sdata[t] - sum + bsum_excl[blockIdx.x];
    #pragma unroll
    for (int k = 0; k < 4; ++k) {
        int i = idx + k;
        if (i < n) rowptr[i] = run;
        run += v[k];
    }
    if (blockIdx.x == 0 && t == 0) rowptr[n] = E;  // total
}

__global__ void copy_int(const int* __restrict__ a, int* __restrict__ b, int n) {
    int i = blockIdx.x * blockDim.x + threadIdx.x;
    if (i < n) b[i] = a[i];
}

// ---------------- CSR fill (counting-sort scatter of edge srcs) ----------------
__global__ void fill_csr(const int* __restrict__ srcv,
                         const int* __restrict__ dstv,
                         const int* __restrict__ etv, int E,
                         int* __restrict__ cursor,
                         int* __restrict__ sorted_src) {
    int e = blockIdx.x * blockDim.x + threadIdx.x;
    if (e < E) {
        int seg = dstv[e] * RNUM + etv[e];
        int pos = atomicAdd(&cursor[seg], 1);
        sorted_src[pos] = srcv[e];
    }
}

// ---------------- fused GEMM (unchanged from R0, passed) ----------------
template<int BM, int BN, int BK, int TM, int TN, int HD>
__global__ __launch_bounds__(256)
void gemm_fused(const float* __restrict__ A,
                const float* __restrict__ Broot,
                const float* __restrict__ Wrel,
                const float* __restrict__ bias,
                float* __restrict__ Cacc,
                float* __restrict__ Crel,
                int M, int K)
{
    constexpr int TX = BN / TN;
    constexpr int TY = BM / TM;
    static_assert(TX * TY == 256, "block must be 256 threads");

    const int tid  = threadIdx.x;
    const int tx   = tid % TX;
    const int ty   = tid / TX;
    const int j0   = blockIdx.x * BN;
    const int row0 = blockIdx.y * BM;

    const bool isRoot = (j0 < HD);
    int r = 0, c0 = j0;
    const float* Bptr;
    if (isRoot) {
        Bptr = Broot + c0;
    } else {
        r  = (j0 - HD) / HD;
        c0 = (j0 - HD) % HD;
        Bptr = Wrel + (size_t)r * K * HD + c0;
    }

    __shared__ float As[BK][BM + 1];
    __shared__ float Bs[BK][BN];

    float acc[TM][TN] = {};

    for (int k0 = 0; k0 < K; k0 += BK) {
        {
            constexpr int KQ = BK / 4;
            int rowi = tid / KQ;
            int kq   = tid % KQ;
            float4 av = make_float4(0.f, 0.f, 0.f, 0.f);
            int grow = row0 + rowi;
            if (grow < M)
                av = *reinterpret_cast<const float4*>(&A[(size_t)grow * K + k0 + kq * 4]);
            As[kq * 4 + 0][rowi] = av.x;
            As[kq * 4 + 1][rowi] = av.y;
            As[kq * 4 + 2][rowi] = av.z;
            As[kq * 4 + 3][rowi] = av.w;
        }
        {
            constexpr int BF4 = BN / 4;
            constexpr int TOT = BK * BF4;
            if (TOT >= 256 || tid < TOT) {
                int k  = tid / BF4;
                int jq = tid % BF4;
                float4 bv = *reinterpret_cast<const float4*>(
                    &Bptr[(size_t)(k0 + k) * HD + jq * 4]);
                *reinterpret_cast<float4*>(&Bs[k][jq * 4]) = bv;
            }
        }
        __syncthreads();

        #pragma unroll
        for (int k = 0; k < BK; ++k) {
            float aF[TM], bF[TN];
            #pragma unroll
            for (int m = 0; m < TM; ++m) aF[m] = As[k][ty * TM + m];
            #pragma unroll
            for (int n = 0; n < TN; ++n) bF[n] = Bs[k][tx * TN + n];
            #pragma unroll
            for (int m = 0; m < TM; ++m)
                #pragma unroll
                for (int n = 0; n < TN; ++n)
                    acc[m][n] += aF[m] * bF[n];
        }
        __syncthreads();
    }

    #pragma unroll
    for (int m = 0; m < TM; ++m) {
        int grow = row0 + ty * TM + m;
        if (grow >= M) continue;
        float tmp[TN];
        #pragma unroll
        for (int n = 0; n < TN; ++n)
            tmp[n] = acc[m][n] + (isRoot ? bias[c0 + tx * TN + n] : 0.f);
        float* dstp = isRoot
            ? &Cacc[(size_t)grow * HD + c0 + tx * TN]
            : &Crel[((size_t)r * M + grow) * HD + c0 + tx * TN];
        if constexpr (TN == 4) {
            *reinterpret_cast<float4*>(dstp) =
                make_float4(tmp[0], tmp[1], tmp[2], tmp[3]);
        } else if constexpr (TN == 2) {
            *reinterpret_cast<float2*>(dstp) = make_float2(tmp[0], tmp[1]);
        } else {
            #pragma unroll
            for (int n = 0; n < TN; ++n) dstp[n] = tmp[n];
        }
    }
}

// ---------------- segmented aggregation (owner-computes, no atomics) ----------------
// block = 256 threads = NPB nodes x HD feats; each thread owns one (node, feat).
template<int HD, int NPB>
__global__ __launch_bounds__(256)
void aggregate(const float* __restrict__ Hrel,      // [R,N,HD]
               const int* __restrict__ rowptr,      // [N*R+1]
               const int* __restrict__ ssrc,        // [E] sorted by seg
               float* __restrict__ outp,            // [N,HD], holds root+bias
               int N)
{
    static_assert(HD * NPB == 256, "");
    int t  = threadIdx.x;
    int f  = t % HD;
    int ln = t / HD;
    int n  = blockIdx.x * NPB + ln;
    if (n >= N) return;

    float acc = 0.f;
    #pragma unroll
    for (int r = 0; r < RNUM; ++r) {
        int seg = n * RNUM + r;
        int beg = rowptr[seg];
        int end = rowptr[seg + 1];
        const float* base = Hrel + (size_t)r * N * HD + f;
        float s = 0.f;
        int e = beg;
        for (; e + 3 < end; e += 4) {           // 4-way ILP on the gather
            int s0 = ssrc[e], s1 = ssrc[e + 1], s2 = ssrc[e + 2], s3 = ssrc[e + 3];
            float v0 = base[(size_t)s0 * HD];
            float v1 = base[(size_t)s1 * HD];
            float v2 = base[(size_t)s2 * HD];
            float v3 = base[(size_t)s3 * HD];
            s += v0 + v1 + v2 + v3;
        }
        for (; e < end; ++e) s += base[(size_t)ssrc[e] * HD];
        int len = end - beg;
        if (len > 0) acc += s * (1.0f / (float)len);
    }
    outp[(size_t)n * HD + f] += acc;
}

__global__ void relu_k(float* __restrict__ p, int n) {
    int i = blockIdx.x * blockDim.x + threadIdx.x;
    if (i < n) p[i] = fmaxf(p[i], 0.f);
}

// ---------------- launch ----------------
extern "C" void kernel_launch(void* const* d_in, const int* in_sizes, int n_in,
                              void* d_out, int out_size, void* d_ws, size_t ws_size,
                              hipStream_t stream)
{
    const float* x     = (const float*)d_in[0];
    const int*   ei    = (const int*)d_in[1];
    const int*   et    = (const int*)d_in[2];
    const float* W1    = (const float*)d_in[3];
    const float* root1 = (const float*)d_in[4];
    const float* b1    = (const float*)d_in[5];
    const float* W2    = (const float*)d_in[6];
    const float* root2 = (const float*)d_in[7];
    const float* b2    = (const float*)d_in[8];
    float* out = (float*)d_out;

    const int N  = in_sizes[0] / IN_DIM;   // 50000
    const int E  = in_sizes[1] / 2;        // 1,600,000
    const int NR = N * RNUM;               // 200,000
    const int* srcv = ei;
    const int* dstv = ei + E;

    // workspace layout:
    // floats: H1[R*N*HID] | hacc[N*HID] | H2[R*N*OUT]
    // ints:   sorted_src[E] | counts/cursor[NR] | rowptr[NR+1] | bsum[...]
    float* H1   = (float*)d_ws;
    float* hacc = H1 + (size_t)RNUM * N * HID;
    float* H2   = hacc + (size_t)N * HID;
    int* sorted_src = (int*)(H2 + (size_t)RNUM * N * OUT_DIM);
    int* counts = sorted_src + E;          // reused as cursor after scan
    int* rowptr = counts + NR;
    int* bsum   = rowptr + NR + 1;

    const int NB_SCAN = (NR + 1023) / 1024;   // 196

    // --- CSR build (shared by both layers)
    hipMemsetAsync(counts, 0, (size_t)NR * sizeof(int), stream);
    count_edges<<<(E + 255) / 256, 256, 0, stream>>>(dstv, et, E, counts);
    scan_reduce<<<NB_SCAN, 256, 0, stream>>>(counts, NR, bsum);
    scan_bsum<<<1, 64, 0, stream>>>(bsum, NB_SCAN);
    scan_apply<<<NB_SCAN, 256, 0, stream>>>(counts, bsum, NR, E, rowptr);
    copy_int<<<(NR + 255) / 256, 256, 0, stream>>>(rowptr, counts, NR); // cursor
    fill_csr<<<(E + 255) / 256, 256, 0, stream>>>(srcv, dstv, et, E, counts, sorted_src);

    // --- layer 1: projections (root -> hacc with bias, relations -> H1)
    dim3 g1((RNUM + 1) * HID / 64, (N + 63) / 64);
    gemm_fused<64, 64, 16, 4, 4, HID>
        <<<g1, 256, 0, stream>>>(x, root1, W1, b1, hacc, H1, N, IN_DIM);

    aggregate<HID, 2><<<(N + 1) / 2, 256, 0, stream>>>(H1, rowptr, sorted_src, hacc, N);

    relu_k<<<(N * HID + 255) / 256, 256, 0, stream>>>(hacc, N * HID);

    // --- layer 2: projections (root -> out with bias, relations -> H2)
    dim3 g2((RNUM + 1) * OUT_DIM / 32, (N + 63) / 64);
    gemm_fused<64, 32, 16, 4, 2, OUT_DIM>
        <<<g2, 256, 0, stream>>>(hacc, root2, W2, b2, out, H2, N, HID);

    aggregate<OUT_DIM, 8><<<(N + 7) / 8, 256, 0, stream>>>(H2, rowptr, sorted_src, out, N);
}

// Round 6
// 942.452 us; speedup vs baseline: 4.8768x; 1.7285x over previous
//
#include <hip/hip_runtime.h>
#include <hip/hip_bf16.h>

// RGCN 2-layer encoder.
// R6: same MFMA bf16x3 layer-1 GEMM as R5, but workspace SHRUNK (138.6 MB vs
// R5's 164.2 MB). R5 core-dumped; only memory-extent change vs the passing R2
// (161.6 MB) was the +2.6 MB wh/wl insertion shifting sorted_src/counts/rowptr
// past R2's proven footprint -> suspected ws overflow. Fix: H2 overlays H1
// (H1 dead after aggregate1, stream-ordered), wh/wl take H2's old slot.
// bf16x3 compensated split: x*w ~= xh*wh + xl*wh + xh*wl, error ~2^-17.

#define RNUM 4
constexpr int IN_DIM  = 1024;
constexpr int HID     = 128;
constexpr int OUT_DIM = 32;

typedef __attribute__((ext_vector_type(8))) short bf16x8;
typedef __attribute__((ext_vector_type(4))) float f32x4;

__device__ inline ushort f2bf(float f) {
    __hip_bfloat16 h = __float2bfloat16(f);
    return *reinterpret_cast<ushort*>(&h);
}
__device__ inline float bf2f(ushort u) {
    __hip_bfloat16 h;
    *reinterpret_cast<ushort*>(&h) = u;
    return __bfloat162float(h);
}

// ---------------- histogram ----------------
__global__ void count_edges(const int* __restrict__ dstv,
                            const int* __restrict__ etv,
                            int E, int* __restrict__ counts) {
    int i = blockIdx.x * blockDim.x + threadIdx.x;
    if (i < E) atomicAdd(&counts[dstv[i] * RNUM + etv[i]], 1);
}

// ---------------- exclusive scan over NR=200k (3 kernels) ----------------
__global__ void scan_reduce(const int* __restrict__ counts, int n,
                            int* __restrict__ bsum) {
    __shared__ int sdata[256];
    int t = threadIdx.x;
    int base = blockIdx.x * 1024;
    int sum = 0;
    #pragma unroll
    for (int k = 0; k < 4; ++k) {
        int i = base + t * 4 + k;
        if (i < n) sum += counts[i];
    }
    sdata[t] = sum; __syncthreads();
    for (int off = 128; off > 0; off >>= 1) {
        if (t < off) sdata[t] += sdata[t + off];
        __syncthreads();
    }
    if (t == 0) bsum[blockIdx.x] = sdata[0];
}

__global__ void scan_bsum(int* __restrict__ bsum, int nb) {
    if (threadIdx.x == 0 && blockIdx.x == 0) {
        int acc = 0;
        for (int i = 0; i < nb; ++i) { int v = bsum[i]; bsum[i] = acc; acc += v; }
    }
}

__global__ void scan_apply(const int* __restrict__ counts,
                           const int* __restrict__ bsum_excl,
                           int n, int E, int* __restrict__ rowptr) {
    __shared__ int sdata[256];
    int t = threadIdx.x;
    int base = blockIdx.x * 1024;
    int idx = base + t * 4;
    int v[4]; int sum = 0;
    #pragma unroll
    for (int k = 0; k < 4; ++k) {
        int i = idx + k;
        v[k] = (i < n) ? counts[i] : 0;
        sum += v[k];
    }
    sdata[t] = sum; __syncthreads();
    for (int off = 1; off < 256; off <<= 1) {
        int x = (t >= off) ? sdata[t - off] : 0;
        __syncthreads();
        sdata[t] += x;
        __syncthreads();
    }
    int run = sdata[t] - sum + bsum_excl[blockIdx.x];
    #pragma unroll
    for (int k = 0; k < 4; ++k) {
        int i = idx + k;
        if (i < n) rowptr[i] = run;
        run += v[k];
    }
    if (blockIdx.x == 0 && t == 0) rowptr[n] = E;
}

__global__ void copy_int(const int* __restrict__ a, int* __restrict__ b, int n) {
    int i = blockIdx.x * blockDim.x + threadIdx.x;
    if (i < n) b[i] = a[i];
}

// ---------------- CSR fill ----------------
__global__ void fill_csr(const int* __restrict__ srcv,
                         const int* __restrict__ dstv,
                         const int* __restrict__ etv, int E,
                         int* __restrict__ cursor,
                         int* __restrict__ sorted_src) {
    int e = blockIdx.x * blockDim.x + threadIdx.x;
    if (e < E) {
        int seg = dstv[e] * RNUM + etv[e];
        int pos = atomicAdd(&cursor[seg], 1);
        sorted_src[pos] = srcv[e];
    }
}

// ---------------- W preconvert: [K][HD] f32 -> [(R+1)*HD][K] bf16 hi/lo ----
__global__ void conv_w(const float* __restrict__ root,
                       const float* __restrict__ Wrel,
                       ushort* __restrict__ wh, ushort* __restrict__ wl) {
    int idx = blockIdx.x * 256 + threadIdx.x;   // (m, n, k), k fastest
    int total = (RNUM + 1) * HID * IN_DIM;
    if (idx >= total) return;
    int k = idx % IN_DIM;
    int t = idx / IN_DIM;
    int n = t % HID;
    int m = t / HID;
    const float* src = (m == 0) ? root : Wrel + (size_t)(m - 1) * IN_DIM * HID;
    float v = src[(size_t)k * HID + n];
    ushort hi = f2bf(v);
    float lo = v - bf2f(hi);
    wh[idx] = hi;
    wl[idx] = f2bf(lo);
}

// ---------------- layer-1 GEMM: MFMA bf16x3 ----------------
// A[M,1024] f32 x W[(root|4 rel)][1024,128] -> Cacc[M,128](+bias) / Crel[4,M,128]
// 128x128 tile, BK=64, 4 waves (2x2), wave tile 64x64 = 4x4 frags 16x16x32.
__global__ __launch_bounds__(256, 2)
void gemm1_mfma(const float* __restrict__ A,
                const ushort* __restrict__ wh,   // [5*128][1024]
                const ushort* __restrict__ wl,
                const float* __restrict__ bias,
                float* __restrict__ Cacc,
                float* __restrict__ Crel,
                int M)
{
    constexpr int K = IN_DIM, BK = 64, BM = 128;
    __shared__ short Ah[BM * BK], Al[BM * BK], Bh[BM * BK], Bl[BM * BK];

    const int tid  = threadIdx.x;
    const int lane = tid & 63;
    const int w    = tid >> 6;
    const int wr   = w >> 1, wc = w & 1;
    const int l15  = lane & 15, lk = lane >> 4;

    const int bid  = blockIdx.x;
    const int cb   = bid % 5;        // 0=root, 1..4 relations
    const int rb   = bid / 5;
    const int row0 = rb * BM;

    const ushort* whp = wh + (size_t)cb * BM * K;
    const ushort* wlp = wl + (size_t)cb * BM * K;

    f32x4 acc[4][4] = {};

    for (int k0 = 0; k0 < K; k0 += BK) {
        // ---- stage A: 4 chunks of 8 f32 per thread -> hi/lo bf16, swizzled
        #pragma unroll
        for (int i = 0; i < 4; ++i) {
            int c   = i * 256 + tid;
            int row = c >> 3, kc = c & 7;
            int gr  = row0 + row; if (gr > M - 1) gr = M - 1;  // clamp (dupes unsaved)
            const float* src = A + (size_t)gr * K + k0 + kc * 8;
            float4 v0 = *reinterpret_cast<const float4*>(src);
            float4 v1 = *reinterpret_cast<const float4*>(src + 4);
            float f[8] = {v0.x, v0.y, v0.z, v0.w, v1.x, v1.y, v1.z, v1.w};
            bf16x8 hv, lv;
            #pragma unroll
            for (int j = 0; j < 8; ++j) {
                ushort h = f2bf(f[j]);
                hv[j] = (short)h;
                lv[j] = (short)f2bf(f[j] - bf2f(h));
            }
            int off = (row * 128 + kc * 16) ^ ((row & 7) << 4);
            *reinterpret_cast<bf16x8*>((char*)Ah + off) = hv;
            *reinterpret_cast<bf16x8*>((char*)Al + off) = lv;
        }
        // ---- stage B: preconverted bf16 rows [n][k], swizzled
        #pragma unroll
        for (int i = 0; i < 4; ++i) {
            int c  = i * 256 + tid;
            int n  = c >> 3, kc = c & 7;
            int off = (n * 128 + kc * 16) ^ ((n & 7) << 4);
            *reinterpret_cast<bf16x8*>((char*)Bh + off) =
                *reinterpret_cast<const bf16x8*>(whp + (size_t)n * K + k0 + kc * 8);
            *reinterpret_cast<bf16x8*>((char*)Bl + off) =
                *reinterpret_cast<const bf16x8*>(wlp + (size_t)n * K + k0 + kc * 8);
        }
        __syncthreads();

        #pragma unroll
        for (int ks = 0; ks < 2; ++ks) {
            bf16x8 a_h[4], a_l[4], b_h[4], b_l[4];
            const int kb = (ks * 32 + lk * 8) * 2;   // byte offset along k
            #pragma unroll
            for (int mf = 0; mf < 4; ++mf) {
                int row = wr * 64 + mf * 16 + l15;
                int off = (row * 128 + kb) ^ ((row & 7) << 4);
                a_h[mf] = *reinterpret_cast<bf16x8*>((char*)Ah + off);
                a_l[mf] = *reinterpret_cast<bf16x8*>((char*)Al + off);
            }
            #pragma unroll
            for (int nf = 0; nf < 4; ++nf) {
                int n   = wc * 64 + nf * 16 + l15;
                int off = (n * 128 + kb) ^ ((n & 7) << 4);
                b_h[nf] = *reinterpret_cast<bf16x8*>((char*)Bh + off);
                b_l[nf] = *reinterpret_cast<bf16x8*>((char*)Bl + off);
            }
            #pragma unroll
            for (int mf = 0; mf < 4; ++mf)
                #pragma unroll
                for (int nf = 0; nf < 4; ++nf) {
                    acc[mf][nf] = __builtin_amdgcn_mfma_f32_16x16x32_bf16(
                        a_h[mf], b_h[nf], acc[mf][nf], 0, 0, 0);
                    acc[mf][nf] = __builtin_amdgcn_mfma_f32_16x16x32_bf16(
                        a_l[mf], b_h[nf], acc[mf][nf], 0, 0, 0);
                    acc[mf][nf] = __builtin_amdgcn_mfma_f32_16x16x32_bf16(
                        a_h[mf], b_l[nf], acc[mf][nf], 0, 0, 0);
                }
        }
        __syncthreads();
    }

    // ---- epilogue: C frag layout col=lane&15, row=(lane>>4)*4+j
    #pragma unroll
    for (int mf = 0; mf < 4; ++mf)
        #pragma unroll
        for (int j = 0; j < 4; ++j) {
            int row = row0 + wr * 64 + mf * 16 + lk * 4 + j;
            if (row >= M) continue;
            #pragma unroll
            for (int nf = 0; nf < 4; ++nf) {
                int col = wc * 64 + nf * 16 + l15;
                float v = acc[mf][nf][j];
                if (cb == 0) Cacc[(size_t)row * HID + col] = v + bias[col];
                else Crel[((size_t)(cb - 1) * M + row) * HID + col] = v;
            }
        }
}

// ---------------- layer-2 GEMM (fp32 vector, small) ----------------
template<int BM, int BN, int BK, int TM, int TN, int HD>
__global__ __launch_bounds__(256)
void gemm_fused(const float* __restrict__ A,
                const float* __restrict__ Broot,
                const float* __restrict__ Wrel,
                const float* __restrict__ bias,
                float* __restrict__ Cacc,
                float* __restrict__ Crel,
                int M, int K)
{
    constexpr int TX = BN / TN;
    constexpr int TY = BM / TM;
    static_assert(TX * TY == 256, "block must be 256 threads");

    const int tid  = threadIdx.x;
    const int tx   = tid % TX;
    const int ty   = tid / TX;
    const int j0   = blockIdx.x * BN;
    const int row0 = blockIdx.y * BM;

    const bool isRoot = (j0 < HD);
    int r = 0, c0 = j0;
    const float* Bptr;
    if (isRoot) {
        Bptr = Broot + c0;
    } else {
        r  = (j0 - HD) / HD;
        c0 = (j0 - HD) % HD;
        Bptr = Wrel + (size_t)r * K * HD + c0;
    }

    __shared__ float As[BK][BM + 1];
    __shared__ float Bs[BK][BN];

    float acc[TM][TN] = {};

    for (int k0 = 0; k0 < K; k0 += BK) {
        {
            constexpr int KQ = BK / 4;
            int rowi = tid / KQ;
            int kq   = tid % KQ;
            float4 av = make_float4(0.f, 0.f, 0.f, 0.f);
            int grow = row0 + rowi;
            if (grow < M)
                av = *reinterpret_cast<const float4*>(&A[(size_t)grow * K + k0 + kq * 4]);
            As[kq * 4 + 0][rowi] = av.x;
            As[kq * 4 + 1][rowi] = av.y;
            As[kq * 4 + 2][rowi] = av.z;
            As[kq * 4 + 3][rowi] = av.w;
        }
        {
            constexpr int BF4 = BN / 4;
            constexpr int TOT = BK * BF4;
            if (TOT >= 256 || tid < TOT) {
                int k  = tid / BF4;
                int jq = tid % BF4;
                float4 bv = *reinterpret_cast<const float4*>(
                    &Bptr[(size_t)(k0 + k) * HD + jq * 4]);
                *reinterpret_cast<float4*>(&Bs[k][jq * 4]) = bv;
            }
        }
        __syncthreads();

        #pragma unroll
        for (int k = 0; k < BK; ++k) {
            float aF[TM], bF[TN];
            #pragma unroll
            for (int m = 0; m < TM; ++m) aF[m] = As[k][ty * TM + m];
            #pragma unroll
            for (int n = 0; n < TN; ++n) bF[n] = Bs[k][tx * TN + n];
            #pragma unroll
            for (int m = 0; m < TM; ++m)
                #pragma unroll
                for (int n = 0; n < TN; ++n)
                    acc[m][n] += aF[m] * bF[n];
        }
        __syncthreads();
    }

    #pragma unroll
    for (int m = 0; m < TM; ++m) {
        int grow = row0 + ty * TM + m;
        if (grow >= M) continue;
        float tmp[TN];
        #pragma unroll
        for (int n = 0; n < TN; ++n)
            tmp[n] = acc[m][n] + (isRoot ? bias[c0 + tx * TN + n] : 0.f);
        float* dstp = isRoot
            ? &Cacc[(size_t)grow * HD + c0 + tx * TN]
            : &Crel[((size_t)r * M + grow) * HD + c0 + tx * TN];
        if constexpr (TN == 4) {
            *reinterpret_cast<float4*>(dstp) =
                make_float4(tmp[0], tmp[1], tmp[2], tmp[3]);
        } else if constexpr (TN == 2) {
            *reinterpret_cast<float2*>(dstp) = make_float2(tmp[0], tmp[1]);
        } else {
            #pragma unroll
            for (int n = 0; n < TN; ++n) dstp[n] = tmp[n];
        }
    }
}

// ---------------- segmented aggregation (owner-computes) ----------------
template<int HD, int NPB, bool RELU>
__global__ __launch_bounds__(256)
void aggregate(const float* __restrict__ Hrel,      // [R,N,HD]
               const int* __restrict__ rowptr,      // [N*R+1]
               const int* __restrict__ ssrc,        // [E] sorted by seg
               float* __restrict__ outp,            // [N,HD], holds root+bias
               int N)
{
    static_assert(HD * NPB == 256, "");
    int t  = threadIdx.x;
    int f  = t % HD;
    int ln = t / HD;
    int n  = blockIdx.x * NPB + ln;
    if (n >= N) return;

    float acc = 0.f;
    #pragma unroll
    for (int r = 0; r < RNUM; ++r) {
        int seg = n * RNUM + r;
        int beg = rowptr[seg];
        int end = rowptr[seg + 1];
        const float* base = Hrel + (size_t)r * N * HD + f;
        float s = 0.f;
        int e = beg;
        for (; e + 3 < end; e += 4) {
            int s0 = ssrc[e], s1 = ssrc[e + 1], s2 = ssrc[e + 2], s3 = ssrc[e + 3];
            float v0 = base[(size_t)s0 * HD];
            float v1 = base[(size_t)s1 * HD];
            float v2 = base[(size_t)s2 * HD];
            float v3 = base[(size_t)s3 * HD];
            s += v0 + v1 + v2 + v3;
        }
        for (; e < end; ++e) s += base[(size_t)ssrc[e] * HD];
        int len = end - beg;
        if (len > 0) acc += s * (1.0f / (float)len);
    }
    float vout = outp[(size_t)n * HD + f] + acc;
    if (RELU) vout = fmaxf(vout, 0.f);
    outp[(size_t)n * HD + f] = vout;
}

// ---------------- launch ----------------
extern "C" void kernel_launch(void* const* d_in, const int* in_sizes, int n_in,
                              void* d_out, int out_size, void* d_ws, size_t ws_size,
                              hipStream_t stream)
{
    const float* x     = (const float*)d_in[0];
    const int*   ei    = (const int*)d_in[1];
    const int*   et    = (const int*)d_in[2];
    const float* W1    = (const float*)d_in[3];
    const float* root1 = (const float*)d_in[4];
    const float* b1    = (const float*)d_in[5];
    const float* W2    = (const float*)d_in[6];
    const float* root2 = (const float*)d_in[7];
    const float* b2    = (const float*)d_in[8];
    float* out = (float*)d_out;

    const int N  = in_sizes[0] / IN_DIM;   // 50000
    const int E  = in_sizes[1] / 2;        // 1,600,000
    const int NR = N * RNUM;               // 200,000
    const int* srcv = ei;
    const int* dstv = ei + E;

    // ws layout (peak 138.6 MB, < R2's proven 161.6 MB):
    //   H1[R*N*HID] f32            (102.4 MB)  -- H2[R*N*OUT] OVERLAYS H1
    //   hacc[N*HID] f32            ( 25.6 MB)
    //   wh, wl [(R+1)*HID*IN] bf16 (  2.6 MB)
    //   sorted_src[E] int          (  6.4 MB)
    //   counts[NR], rowptr[NR+1], bsum ints
    // Hazard check: wh/wl disjoint from H1/hacc (read by gemm1 while it writes
    // H1+hacc). H2 overlays H1: H1's last reader (aggregate1) precedes gemm2's
    // H2 writes in stream order.
    float*  H1   = (float*)d_ws;
    float*  H2   = H1;                                   // overlay (see above)
    float*  hacc = H1 + (size_t)RNUM * N * HID;
    ushort* wh   = (ushort*)(hacc + (size_t)N * HID);
    ushort* wl   = wh + (size_t)(RNUM + 1) * HID * IN_DIM;
    int* sorted_src = (int*)(wl + (size_t)(RNUM + 1) * HID * IN_DIM);
    int* counts = sorted_src + E;
    int* rowptr = counts + NR;
    int* bsum   = rowptr + NR + 1;

    const int NB_SCAN = (NR + 1023) / 1024;

    // --- CSR build (shared by both layers)
    hipMemsetAsync(counts, 0, (size_t)NR * sizeof(int), stream);
    count_edges<<<(E + 255) / 256, 256, 0, stream>>>(dstv, et, E, counts);
    scan_reduce<<<NB_SCAN, 256, 0, stream>>>(counts, NR, bsum);
    scan_bsum<<<1, 64, 0, stream>>>(bsum, NB_SCAN);
    scan_apply<<<NB_SCAN, 256, 0, stream>>>(counts, bsum, NR, E, rowptr);
    copy_int<<<(NR + 255) / 256, 256, 0, stream>>>(rowptr, counts, NR);
    fill_csr<<<(E + 255) / 256, 256, 0, stream>>>(srcv, dstv, et, E, counts, sorted_src);

    // --- W1 preconvert (hi/lo, transposed to [n][k])
    int wtot = (RNUM + 1) * HID * IN_DIM;
    conv_w<<<(wtot + 255) / 256, 256, 0, stream>>>(root1, W1, wh, wl);

    // --- layer 1: MFMA projections (root -> hacc+bias, relations -> H1)
    int gy = (N + 127) / 128;
    gemm1_mfma<<<5 * gy, 256, 0, stream>>>(x, wh, wl, b1, hacc, H1, N);

    aggregate<HID, 2, true><<<(N + 1) / 2, 256, 0, stream>>>(
        H1, rowptr, sorted_src, hacc, N);   // += agg, then ReLU (fused)

    // --- layer 2: fp32 projections (root -> out+bias, relations -> H2)
    dim3 g2((RNUM + 1) * OUT_DIM / 32, (N + 63) / 64);
    gemm_fused<64, 32, 16, 4, 2, OUT_DIM>
        <<<g2, 256, 0, stream>>>(hacc, root2, W2, b2, out, H2, N, HID);

    aggregate<OUT_DIM, 8, false><<<(N + 7) / 8, 256, 0, stream>>>(
        H2, rowptr, sorted_src, out, N);
}